// Round 10
// baseline (876.576 us; speedup 1.0000x reference)
//
#include <hip/hip_runtime.h>
#include <hip/hip_bf16.h>

// BasicAttn: B=2,H=8,S=4096,DK=64. Outputs: context (B,H,S,DK) f32 then attn (B,H,S,S) f32.
// Round 10: STORE CONTIGUITY. All prior rounds issued attn stores whose 64 lanes
// covered 16 rows x 64B (scattered segments/instr) -> pinned ~1.5 TB/s. fillBuffer
// (1KB contiguous per instr) hits 6.5 TB/s. This round: producer/consumer waves as
// r9, but P staged in 4-tile groups (16 rows x 256 keys bf16) and store waves emit
// ONE 1KB fully-contiguous f32x4 store per row (fillBuffer pattern).
// Compute waves: loads-only vmcnt; store waves: stores-only, never waited.

typedef __bf16 bf16x8 __attribute__((ext_vector_type(8)));
typedef __bf16 bf16x4 __attribute__((ext_vector_type(4)));
typedef float f32x4 __attribute__((ext_vector_type(4)));

#define BH 16
#define SEQ 4096
#define DKD 64
#define GSTRIDE 264  // bf16 elems per staged row (4*64 keys + 8 pad); 528B, 16B-aligned
#define LOG2E 1.44269504088896f

__global__ void cvt_bf16_kernel(const float* __restrict__ src,
                                __bf16* __restrict__ dst, int n4, float scale) {
    int i = blockIdx.x * blockDim.x + threadIdx.x;
    if (i < n4) {
        const float4 v = reinterpret_cast<const float4*>(src)[i];
        bf16x4 o;
        o[0] = (__bf16)(v.x * scale); o[1] = (__bf16)(v.y * scale);
        o[2] = (__bf16)(v.z * scale); o[3] = (__bf16)(v.w * scale);
        reinterpret_cast<bf16x4*>(dst)[i] = o;
    }
}

// V[head][s][d] (f32) -> Vt[head][d][s] (bf16), 64x64 tiles through LDS.
__global__ void transpose_v_kernel(const float* __restrict__ V,
                                   __bf16* __restrict__ Vt) {
    __shared__ __bf16 T[DKD][72];
    const int head = blockIdx.y;
    const int s0 = blockIdx.x * 64;
    const int t = threadIdx.x;
    const float* vp = V + ((size_t)head * SEQ + s0) * DKD;
#pragma unroll
    for (int i = 0; i < 16; ++i) {
        int j = i * 256 + t;            // j = s*64 + d, coalesced read
        T[j & 63][j >> 6] = (__bf16)vp[j];
    }
    __syncthreads();
    __bf16* op = Vt + (size_t)head * DKD * SEQ + s0;
#pragma unroll
    for (int i = 0; i < 16; ++i) {
        int j = i * 256 + t;            // j = d*64 + s, coalesced write
        op[(size_t)(j >> 6) * SEQ + (j & 63)] = T[j >> 6][j & 63];
    }
}

__global__ __launch_bounds__(256, 4) void attn_kernel(
    const __bf16* __restrict__ Qb, const __bf16* __restrict__ Kb,
    const __bf16* __restrict__ Vt, float* __restrict__ out_ctx,
    float* __restrict__ out_attn) {
    // P handoff: [buf][compute-wave][row][4 tiles * 64 keys (+pad)] bf16 = 33.8KB.
    __shared__ __align__(16) __bf16 Pg[2][2][16][GSTRIDE];
    __shared__ float Lsum[4][16];

    const int tid = threadIdx.x;
    const int w = tid >> 6;      // 0,1 compute; 2,3 store
    const int lane = tid & 63;
    const int c16 = lane & 15;   // q-row within the 16-row subtile
    const int g = lane >> 4;     // key/dim 4-group (0..3)
    const int qsub = w & 1;      // q-subtile (compute w pairs with store w+2)
    const int khalf = w >> 1;    // pass-A K-half

    // XCD head affinity: xcd = wg % 8 serves heads {2*xcd, 2*xcd+1}.
    const int wg = blockIdx.x;
    const int head = ((wg & 7) << 1) | ((wg >> 3) & 1);
    const int qblk = wg >> 4;               // 0..127 (32-row blocks)
    const int qbase = qblk * 32 + qsub * 16;

    // Q fragments (B operand of swapped QK^T): Q[qbase+c16][g*8..+7], scaled 1/8.
    const __bf16* qp = Qb + ((size_t)head * SEQ + qbase + c16) * DKD + g * 8;
    const bf16x8 qf0 = *reinterpret_cast<const bf16x8*>(qp);
    const bf16x8 qf1 = *reinterpret_cast<const bf16x8*>(qp + 32);

    const __bf16* kbase = Kb + (size_t)head * SEQ * DKD;
    const __bf16* vbase = Vt + (size_t)head * DKD * SEQ;
    float* attn_p = out_attn + ((size_t)head * SEQ + qbase) * SEQ;

    // ---- Pass A (all 4 waves, K-split): per-lane sum of exp2 over 32 tiles ----
    float lsum = 0.f;
    for (int t = 0; t < 32; ++t) {
        const int kt = (khalf * 32 + t) * 64;
#pragma unroll
        for (int ct = 0; ct < 4; ++ct) {
            const __bf16* kp = kbase + (size_t)(kt + ct * 16 + c16) * DKD + g * 8;
            bf16x8 kf0 = *reinterpret_cast<const bf16x8*>(kp);
            bf16x8 kf1 = *reinterpret_cast<const bf16x8*>(kp + 32);
            f32x4 a = (f32x4){0.f, 0.f, 0.f, 0.f};
            a = __builtin_amdgcn_mfma_f32_16x16x32_bf16(kf0, qf0, a, 0, 0, 0);
            a = __builtin_amdgcn_mfma_f32_16x16x32_bf16(kf1, qf1, a, 0, 0, 0);
            float e0 = __builtin_amdgcn_exp2f(a[0] * LOG2E);
            float e1 = __builtin_amdgcn_exp2f(a[1] * LOG2E);
            float e2 = __builtin_amdgcn_exp2f(a[2] * LOG2E);
            float e3 = __builtin_amdgcn_exp2f(a[3] * LOG2E);
            lsum += (e0 + e1) + (e2 + e3);
        }
    }
    lsum += __shfl_xor(lsum, 16);
    lsum += __shfl_xor(lsum, 32);
    if (g == 0) Lsum[w][c16] = lsum;
    __syncthreads();  // one-time drain before the pipelined phase (loads only)

    if (w < 2) {
        // ================= COMPUTE WAVE: loads-only vmcnt stream =================
        const float inv_l = __builtin_amdgcn_rcpf(Lsum[w][c16] + Lsum[w ^ 2][c16]);

        f32x4 o[4];
#pragma unroll
        for (int dt = 0; dt < 4; ++dt) o[dt] = (f32x4){0.f, 0.f, 0.f, 0.f};

        // S for tile (4*grp+s): 2 halves of 32 keys (acc[2] live), bf16 P -> slot s.
        auto computeS = [&](int t, int s, __bf16(*Pbuf)[GSTRIDE]) {
            const int kt = t * 64;
#pragma unroll
            for (int h = 0; h < 2; ++h) {
                f32x4 acc[2];
#pragma unroll
                for (int ct = 0; ct < 2; ++ct) {
                    acc[ct] = (f32x4){0.f, 0.f, 0.f, 0.f};
                    const __bf16* kp =
                        kbase + (size_t)(kt + h * 32 + ct * 16 + c16) * DKD + g * 8;
                    bf16x8 kf0 = *reinterpret_cast<const bf16x8*>(kp);
                    bf16x8 kf1 = *reinterpret_cast<const bf16x8*>(kp + 32);
                    acc[ct] = __builtin_amdgcn_mfma_f32_16x16x32_bf16(kf0, qf0, acc[ct], 0, 0, 0);
                    acc[ct] = __builtin_amdgcn_mfma_f32_16x16x32_bf16(kf1, qf1, acc[ct], 0, 0, 0);
                }
#pragma unroll
                for (int ct = 0; ct < 2; ++ct) {
                    bf16x4 pb;
#pragma unroll
                    for (int r = 0; r < 4; ++r)
                        pb[r] = (__bf16)(__builtin_amdgcn_exp2f(acc[ct][r] * LOG2E) * inv_l);
                    *reinterpret_cast<bf16x4*>(
                        &Pbuf[c16][s * 64 + h * 32 + ct * 16 + g * 4]) = pb;
                }
            }
        };

        // PV for tile (4*grp+s): bf16 P frags from slot s, O^T += V^T x P^T.
        auto pvTile = [&](int t, int s, const __bf16(*Pbuf)[GSTRIDE]) {
            const int kt = t * 64;
            bf16x8 pb0 = *reinterpret_cast<const bf16x8*>(&Pbuf[c16][s * 64 + g * 8]);
            bf16x8 pb1 = *reinterpret_cast<const bf16x8*>(&Pbuf[c16][s * 64 + g * 8 + 32]);
#pragma unroll
            for (int dt = 0; dt < 4; ++dt) {
                const __bf16* vp = vbase + (size_t)(dt * 16 + c16) * SEQ + kt + g * 8;
                bf16x8 vf0 = *reinterpret_cast<const bf16x8*>(vp);
                bf16x8 vf1 = *reinterpret_cast<const bf16x8*>(vp + 32);
                o[dt] = __builtin_amdgcn_mfma_f32_16x16x32_bf16(vf0, pb0, o[dt], 0, 0, 0);
                o[dt] = __builtin_amdgcn_mfma_f32_16x16x32_bf16(vf1, pb1, o[dt], 0, 0, 0);
            }
        };

        for (int grp = 0; grp < 16; ++grp) {
            __bf16(*buf)[GSTRIDE] = Pg[grp & 1][w];
            const int t0 = grp * 4;
            computeS(t0 + 0, 0, buf);
            computeS(t0 + 1, 1, buf);
            pvTile(t0 + 0, 0, buf);
            computeS(t0 + 2, 2, buf);
            pvTile(t0 + 1, 1, buf);
            computeS(t0 + 3, 3, buf);
            pvTile(t0 + 2, 2, buf);
            pvTile(t0 + 3, 3, buf);
            asm volatile("s_waitcnt lgkmcnt(0)" ::: "memory");
            __builtin_amdgcn_s_barrier();
            __builtin_amdgcn_sched_barrier(0);
        }

        float* ctx_p = out_ctx + ((size_t)head * SEQ + qbase) * DKD;
#pragma unroll
        for (int dt = 0; dt < 4; ++dt)
            *reinterpret_cast<f32x4*>(ctx_p + (size_t)c16 * DKD + dt * 16 + g * 4) = o[dt];
    } else {
        // ============ STORE WAVE: 1KB-contiguous stores, never waited ============
        // Per group: 16 rows; per row ONE instr: 64 lanes x f32x4 = 1KB contiguous.
        for (int grp = 0; grp < 16; ++grp) {
            __builtin_amdgcn_s_barrier();
            __builtin_amdgcn_sched_barrier(0);
            const __bf16(*buf)[GSTRIDE] = Pg[grp & 1][qsub];
            const int k0 = grp * 256;
#pragma unroll
            for (int r = 0; r < 16; ++r) {
                bf16x4 pb = *reinterpret_cast<const bf16x4*>(&buf[r][lane * 4]);
                f32x4 v;
#pragma unroll
                for (int j = 0; j < 4; ++j) v[j] = (float)pb[j];
                *reinterpret_cast<f32x4*>(attn_p + (size_t)r * SEQ + k0 + lane * 4) = v;
            }
        }
        // Stores drain at end-of-kernel; never waited on in the loop.
    }
}

extern "C" void kernel_launch(void* const* d_in, const int* in_sizes, int n_in,
                              void* d_out, int out_size, void* d_ws, size_t ws_size,
                              hipStream_t stream) {
    const float* Q = (const float*)d_in[0];
    const float* K = (const float*)d_in[1];
    const float* V = (const float*)d_in[2];
    float* out = (float*)d_out;

    const size_t nElem = (size_t)BH * SEQ * DKD;  // 4,194,304
    __bf16* Qb = (__bf16*)d_ws;
    __bf16* Kb = Qb + nElem;
    __bf16* Vt = Kb + nElem;

    float* out_ctx = out;
    float* out_attn = out + nElem;  // context first, then attn

    const int n4 = (int)(nElem / 4);
    cvt_bf16_kernel<<<dim3((n4 + 255) / 256), dim3(256), 0, stream>>>(Q, Qb, n4, 0.125f);
    cvt_bf16_kernel<<<dim3((n4 + 255) / 256), dim3(256), 0, stream>>>(K, Kb, n4, 1.0f);
    transpose_v_kernel<<<dim3(64, BH), dim3(256), 0, stream>>>(V, Vt);
    attn_kernel<<<dim3(BH * SEQ / 32), dim3(256), 0, stream>>>(Qb, Kb, Vt, out_ctx, out_attn);
}